// Round 7
// baseline (3386.712 us; speedup 1.0000x reference)
//
#include <hip/hip_runtime.h>

// ECGLSTM: B=256, T=5000, input_size=1, H=64, fused FC(64->128)+ReLU.
// R7 = R6 + (a) opaque-asm weight pinning, (b) 2-way batch multiplexing.
// (a) R5/R6 showed VGPR_Count=48: the compiler rematerializes the loop-
//     invariant W_hh loads INSIDE the 5000-step loop (launch_bounds alone
//     doesn't stop it). asm volatile("" : "+v"(w[i])) makes the loaded
//     values opaque -> cannot be rematerialized -> weights stay in VGPRs,
//     zero global loads in the recurrence.
// (b) The chain is latency-bound (VALUBusy 23%, 1 wave/SIMD). Two
//     INDEPENDENT batch elements per block (grid=128) share the same
//     weight registers and the same barrier; their serial chains
//     interleave, hiding each other's LDS/transcendental latency.
// Structure per element: thread tid owns gate tid; replicated c/h update
// in all 4 waves; ONE barrier/step; double-buffered gates+h; x staged to
// LDS once. Arithmetic identical to R1/R5/R6 (absmax 3.8e-6).

#define LSTM_H 64
#define LSTM_T 5000
#define LSTM_B 256
#define NB     2                    // batch elements per block
#define NBLK   (LSTM_B / NB)        // 128 blocks

typedef float v2f __attribute__((ext_vector_type(2)));

__device__ __forceinline__ void pk_fma_acc(v2f& acc, v2f a, v2f b) {
    // acc = a*b + acc in place (tied operand -> no v_mov)
    asm("v_pk_fma_f32 %0, %1, %2, %0" : "+v"(acc) : "v"(a), "v"(b));
}

__device__ __forceinline__ float fast_rcp(float v) {
    return __builtin_amdgcn_rcpf(v);
}

__global__ __launch_bounds__(256, 1) void ECGLSTM_lstm_fused(
    const float* __restrict__ x,      // [B, T]
    const float* __restrict__ W_ih,   // [4H, 1]
    const float* __restrict__ W_hh,   // [4H, H]
    const float* __restrict__ b_ih,   // [4H]
    const float* __restrict__ b_hh,   // [4H]
    const float* __restrict__ W_fc,   // [128, H]
    const float* __restrict__ b_fc,   // [128]
    float* __restrict__ out)          // [B, 128]
{
    const int tid  = threadIdx.x;     // gate index 0..255
    const int lane = tid & 63;        // hidden unit this thread updates
    const int b0   = blockIdx.x * NB; // first batch element of this block

    __shared__ float xch[NB][LSTM_T];           // x rows, staged once (40 KB)
    __shared__ float hbuf[NB][2][LSTM_H];       // double-buffered h
    __shared__ float gbuf[NB][2][4 * LSTM_H];   // double-buffered gates

    // Stage both x rows (coalesced, once)
    #pragma unroll
    for (int nb = 0; nb < NB; ++nb) {
        const float* xb = x + (b0 + nb) * LSTM_T;
        for (int i = tid; i < LSTM_T; i += 256) xch[nb][i] = xb[i];
    }

    // W_hh row `tid` -> 32 v2f (64 VGPRs), shared by both batch elements
    v2f w[LSTM_H / 2];
    {
        const float4* wrow = reinterpret_cast<const float4*>(W_hh + tid * LSTM_H);
        #pragma unroll
        for (int i = 0; i < LSTM_H / 4; ++i) {
            float4 v = wrow[i];
            w[2 * i]     = v2f{v.x, v.y};
            w[2 * i + 1] = v2f{v.z, v.w};
        }
    }
    // PIN: make w unrematerializable -> forced VGPR residency across the loop
    #pragma unroll
    for (int i = 0; i < LSTM_H / 2; ++i) asm volatile("" : "+v"(w[i]));

    float wih  = W_ih[tid];
    float bias = b_ih[tid] + b_hh[tid];
    asm volatile("" : "+v"(wih), "+v"(bias));   // pin these too
    const bool is_tanh = ((tid >> 6) == 2);     // wave-uniform branch

    float cA = 0.0f, cB = 0.0f;       // replicated cell state per element
    hbuf[0][0][lane] = 0.0f;          // every wave writes full h0
    hbuf[1][0][lane] = 0.0f;
    __syncthreads();                  // x staged + h0 visible

    // One dual-element LSTM step at parity P.
    #define LSTM_STEP(t, P)                                                    \
    {                                                                          \
        const float xvA = xch[0][(t)];                                         \
        const float xvB = xch[1][(t)];                                         \
        v2f AA = {0.f,0.f}, CA = {0.f,0.f};                                    \
        v2f AB = {0.f,0.f}, CB = {0.f,0.f};                                    \
        const float4* hA = reinterpret_cast<const float4*>(hbuf[0][(P)]);      \
        const float4* hB = reinterpret_cast<const float4*>(hbuf[1][(P)]);      \
        _Pragma("unroll")                                                      \
        for (int i = 0; i < LSTM_H / 4; ++i) {                                 \
            float4 ha = hA[i];                       /* b128 broadcast */      \
            float4 hb = hB[i];                                                 \
            pk_fma_acc(AA, v2f{ha.x, ha.y}, w[2 * i]);                         \
            pk_fma_acc(CA, v2f{ha.z, ha.w}, w[2 * i + 1]);                     \
            pk_fma_acc(AB, v2f{hb.x, hb.y}, w[2 * i]);                         \
            pk_fma_acc(CB, v2f{hb.z, hb.w}, w[2 * i + 1]);                     \
        }                                                                      \
        float gA = fmaf(xvA, wih, bias) + ((AA.x + AA.y) + (CA.x + CA.y));     \
        float gB = fmaf(xvB, wih, bias) + ((AB.x + AB.y) + (CB.x + CB.y));     \
        float actA, actB;                                                      \
        if (is_tanh) {                                                         \
            float eA = __expf(2.0f * gA);                                      \
            actA = 1.0f - 2.0f * fast_rcp(eA + 1.0f);                          \
            float eB = __expf(2.0f * gB);                                      \
            actB = 1.0f - 2.0f * fast_rcp(eB + 1.0f);                          \
        } else {                                                               \
            float eA = __expf(-gA);                                            \
            actA = fast_rcp(1.0f + eA);                                        \
            float eB = __expf(-gB);                                            \
            actB = fast_rcp(1.0f + eB);                                        \
        }                                                                      \
        gbuf[0][(P)][tid] = actA;                                              \
        gbuf[1][(P)][tid] = actB;                                              \
        __syncthreads();                             /* the ONE barrier */     \
        {                                                                      \
            const float ig = gbuf[0][(P)][lane];                               \
            const float fg = gbuf[0][(P)][LSTM_H + lane];                      \
            const float gg = gbuf[0][(P)][2 * LSTM_H + lane];                  \
            const float og = gbuf[0][(P)][3 * LSTM_H + lane];                  \
            cA = fmaf(fg, cA, ig * gg);                                        \
            float e2 = __expf(2.0f * cA);                                      \
            float th = 1.0f - 2.0f * fast_rcp(e2 + 1.0f);                      \
            hbuf[0][1 - (P)][lane] = og * th;        /* all waves, same */     \
        }                                                                      \
        {                                                                      \
            const float ig = gbuf[1][(P)][lane];                               \
            const float fg = gbuf[1][(P)][LSTM_H + lane];                      \
            const float gg = gbuf[1][(P)][2 * LSTM_H + lane];                  \
            const float og = gbuf[1][(P)][3 * LSTM_H + lane];                  \
            cB = fmaf(fg, cB, ig * gg);                                        \
            float e2 = __expf(2.0f * cB);                                      \
            float th = 1.0f - 2.0f * fast_rcp(e2 + 1.0f);                      \
            hbuf[1][1 - (P)][lane] = og * th;                                  \
        }                                                                      \
    }

    for (int t = 0; t < LSTM_T; t += 2) {
        LSTM_STEP(t, 0);
        LSTM_STEP(t + 1, 1);
    }
    #undef LSTM_STEP

    // Final h in hbuf[nb][0] (T even); each wave wrote it itself -> no barrier.
    // FC(64->128)+ReLU for both elements: threads 0..127, one row each.
    if (tid < 128) {
        const float4* wf = reinterpret_cast<const float4*>(W_fc + tid * LSTM_H);
        float4 wv[LSTM_H / 4];
        #pragma unroll
        for (int i = 0; i < LSTM_H / 4; ++i) wv[i] = wf[i];
        const float bf = b_fc[tid];
        #pragma unroll
        for (int nb = 0; nb < NB; ++nb) {
            float s = bf;
            const float4* h4 = reinterpret_cast<const float4*>(hbuf[nb][0]);
            #pragma unroll
            for (int i = 0; i < LSTM_H / 4; ++i) {
                float4 hv = h4[i];
                s = fmaf(hv.x, wv[i].x, s);
                s = fmaf(hv.y, wv[i].y, s);
                s = fmaf(hv.z, wv[i].z, s);
                s = fmaf(hv.w, wv[i].w, s);
            }
            out[(b0 + nb) * 128 + tid] = fmaxf(s, 0.0f);
        }
    }
}

extern "C" void kernel_launch(void* const* d_in, const int* in_sizes, int n_in,
                              void* d_out, int out_size, void* d_ws, size_t ws_size,
                              hipStream_t stream) {
    const float* x    = (const float*)d_in[0];
    const float* W_ih = (const float*)d_in[1];
    const float* W_hh = (const float*)d_in[2];
    const float* b_ih = (const float*)d_in[3];
    const float* b_hh = (const float*)d_in[4];
    const float* W_fc = (const float*)d_in[5];
    const float* b_fc = (const float*)d_in[6];
    float* out = (float*)d_out;

    ECGLSTM_lstm_fused<<<NBLK, 256, 0, stream>>>(
        x, W_ih, W_hh, b_ih, b_hh, W_fc, b_fc, out);
}

// Round 9
// 2084.273 us; speedup vs baseline: 1.6249x; 1.6249x over previous
//
#include <hip/hip_runtime.h>

// ECGLSTM: B=256, T=5000, input_size=1, H=64, fused FC(64->128)+ReLU.
// R9 = R6 structure + opaque-asm weight pinning (R7's proven lever),
// grid=256 (1 block/CU). R8's ds_read2_b32 inline asm failed to compile
// (DS vaddr must be a 32-bit LDS address VGPR; "v"(ptr) passed a 64-bit
// generic pointer pair) -> reverted to plain C gate reads (compiler emits
// DS ops itself).
// Evidence trail: R5/R6 VGPR_Count=48 = compiler rematerialized the W_hh
// loads inside the 5000-step loop (every step paid global-load latency +
// vmcnt drain at the barrier). R7's pin raised VGPR to 84 = resident.
// Structure: block=256 (4 waves) per batch element; thread tid owns gate
// tid (32 v2f = 64 weight VGPRs); c/h update replicated in all 4 waves
// (each wave writes its own full h copy -> reads only its own writes,
// lgkmcnt-ordered); ONE barrier/step; double-buffered gates+h; x staged to
// LDS once (zero global loads in the loop).
// Arithmetic identical to R1/R5/R6 (absmax 3.814697e-06).

#define LSTM_H 64
#define LSTM_T 5000
#define LSTM_B 256

typedef float v2f __attribute__((ext_vector_type(2)));

__device__ __forceinline__ void pk_fma_acc(v2f& acc, v2f a, v2f b) {
    // acc = a*b + acc in place (tied operand -> no v_mov)
    asm("v_pk_fma_f32 %0, %1, %2, %0" : "+v"(acc) : "v"(a), "v"(b));
}

__device__ __forceinline__ float fast_rcp(float v) {
    return __builtin_amdgcn_rcpf(v);
}

__global__ __launch_bounds__(256, 1) void ECGLSTM_lstm_fused(
    const float* __restrict__ x,      // [B, T]
    const float* __restrict__ W_ih,   // [4H, 1]
    const float* __restrict__ W_hh,   // [4H, H]
    const float* __restrict__ b_ih,   // [4H]
    const float* __restrict__ b_hh,   // [4H]
    const float* __restrict__ W_fc,   // [128, H]
    const float* __restrict__ b_fc,   // [128]
    float* __restrict__ out)          // [B, 128]
{
    const int tid  = threadIdx.x;     // gate index 0..255
    const int lane = tid & 63;        // hidden unit this thread updates
    const int b    = blockIdx.x;

    __shared__ float xch[LSTM_T];             // whole x row, staged once (20 KB)
    __shared__ float hbuf[2][LSTM_H];         // double-buffered h
    __shared__ float gbuf[2][4 * LSTM_H];     // double-buffered gates

    // Stage x (coalesced, once)
    const float* xb = x + b * LSTM_T;
    for (int i = tid; i < LSTM_T; i += 256) xch[i] = xb[i];

    // W_hh row `tid` -> 32 v2f (64 VGPRs)
    v2f w[LSTM_H / 2];
    {
        const float4* wrow = reinterpret_cast<const float4*>(W_hh + tid * LSTM_H);
        #pragma unroll
        for (int i = 0; i < LSTM_H / 4; ++i) {
            float4 v = wrow[i];
            w[2 * i]     = v2f{v.x, v.y};
            w[2 * i + 1] = v2f{v.z, v.w};
        }
    }
    // PIN: make w unrematerializable -> forced VGPR residency (R7: VGPR 48->84)
    #pragma unroll
    for (int i = 0; i < LSTM_H / 2; ++i) asm volatile("" : "+v"(w[i]));

    float wih  = W_ih[tid];
    float bias = b_ih[tid] + b_hh[tid];
    asm volatile("" : "+v"(wih), "+v"(bias));   // pin these too
    const bool is_tanh = ((tid >> 6) == 2);     // wave-uniform branch

    float c = 0.0f;                   // replicated: lane j of every wave has c[j]
    hbuf[0][lane] = 0.0f;             // every wave writes full h0 (identical)
    __syncthreads();                  // x staged + h0 visible

    // One LSTM step at parity P: read hbuf[P]/gbuf[P], write hbuf[1-P].
    #define LSTM_STEP(t, P)                                                    \
    {                                                                          \
        const float xv = xch[(t)];                      /* broadcast b32 */    \
        v2f A = {0.f, 0.f}, C = {0.f, 0.f};                                    \
        const float4* h4 = reinterpret_cast<const float4*>(hbuf[(P)]);         \
        _Pragma("unroll")                                                      \
        for (int i = 0; i < LSTM_H / 4; ++i) {                                 \
            float4 hv = h4[i];                          /* b128 broadcast */   \
            pk_fma_acc(A, v2f{hv.x, hv.y}, w[2 * i]);                          \
            pk_fma_acc(C, v2f{hv.z, hv.w}, w[2 * i + 1]);                      \
        }                                                                      \
        float g = fmaf(xv, wih, bias) + ((A.x + A.y) + (C.x + C.y));           \
        float act;                                                             \
        if (is_tanh) {                                                         \
            float e = __expf(2.0f * g);                                        \
            act = 1.0f - 2.0f * fast_rcp(e + 1.0f);                            \
        } else {                                                               \
            float e = __expf(-g);                                              \
            act = fast_rcp(1.0f + e);                                          \
        }                                                                      \
        gbuf[(P)][tid] = act;                                                  \
        __syncthreads();                                /* the ONE barrier */  \
        const float ig = gbuf[(P)][lane];                                      \
        const float fg = gbuf[(P)][LSTM_H + lane];                             \
        const float gg = gbuf[(P)][2 * LSTM_H + lane];                         \
        const float og = gbuf[(P)][3 * LSTM_H + lane];                         \
        c = fmaf(fg, c, ig * gg);                                              \
        float e2 = __expf(2.0f * c);                                           \
        float th = 1.0f - 2.0f * fast_rcp(e2 + 1.0f);                          \
        hbuf[1 - (P)][lane] = og * th;                  /* all waves, same */  \
    }

    for (int t = 0; t < LSTM_T; t += 2) {
        LSTM_STEP(t, 0);
        LSTM_STEP(t + 1, 1);
    }
    #undef LSTM_STEP

    // Final h is in hbuf[0] (T even); each wave wrote it itself -> no barrier.
    // FC(64->128)+ReLU: threads 0..127 compute one output row each.
    if (tid < 128) {
        float s = b_fc[tid];
        const float4* wf = reinterpret_cast<const float4*>(W_fc + tid * LSTM_H);
        const float4* h4 = reinterpret_cast<const float4*>(hbuf[0]);
        #pragma unroll
        for (int i = 0; i < LSTM_H / 4; ++i) {
            float4 wv = wf[i];
            float4 hv = h4[i];
            s = fmaf(hv.x, wv.x, s);
            s = fmaf(hv.y, wv.y, s);
            s = fmaf(hv.z, wv.z, s);
            s = fmaf(hv.w, wv.w, s);
        }
        out[b * 128 + tid] = fmaxf(s, 0.0f);
    }
}

extern "C" void kernel_launch(void* const* d_in, const int* in_sizes, int n_in,
                              void* d_out, int out_size, void* d_ws, size_t ws_size,
                              hipStream_t stream) {
    const float* x    = (const float*)d_in[0];
    const float* W_ih = (const float*)d_in[1];
    const float* W_hh = (const float*)d_in[2];
    const float* b_ih = (const float*)d_in[3];
    const float* b_hh = (const float*)d_in[4];
    const float* W_fc = (const float*)d_in[5];
    const float* b_fc = (const float*)d_in[6];
    float* out = (float*)d_out;

    ECGLSTM_lstm_fused<<<LSTM_B, 256, 0, stream>>>(
        x, W_ih, W_hh, b_ih, b_hh, W_fc, b_fc, out);
}